// Round 3
// baseline (480.797 us; speedup 1.0000x reference)
//
#include <hip/hip_runtime.h>
#include <hip/hip_bf16.h>

#define DFEAT 64

// ---------------- kernels ----------------

// deg = 1.0 (self-loop contribution to degree)
__global__ __launch_bounds__(256) void init_kernel(float* deg, int n) {
    int i = blockIdx.x * blockDim.x + threadIdx.x;
    if (i < n) deg[i] = 1.0f;
}

// deg[dst] += 1 per edge
__global__ __launch_bounds__(256) void degree_kernel(const int* __restrict__ ei, float* deg, int E) {
    int e = blockIdx.x * blockDim.x + threadIdx.x;
    if (e < E) atomicAdd(&deg[ei[E + e]], 1.0f);
}

// deg <- deg^{-1/2}  (deg >= 1 always)
__global__ __launch_bounds__(256) void dinv_kernel(float* deg, int n) {
    int i = blockIdx.x * blockDim.x + threadIdx.x;
    if (i < n) deg[i] = rsqrtf(deg[i]);
}

// Seed accumulator (== d_out) with the self-loop term: acc[node][c] = x[node][c]*dinv[node]^2
// Assignment (not +=) so the 0xAA poison in d_out never matters.
__global__ __launch_bounds__(256) void seed_kernel(const float* __restrict__ x,
                                                   const float* __restrict__ dinv,
                                                   float* __restrict__ acc, int n) {
    int i = blockIdx.x * blockDim.x + threadIdx.x;   // node*64 + c
    int node = i >> 6;
    if (node >= n) return;
    float di = dinv[node];
    acc[i] = x[i] * di * di;
}

// One 64-lane wave per edge: acc[dst][lane] += x[src][lane] * dinv[src]*dinv[dst]
// (aggregate BEFORE the linear layer: S·(XW) == (S·X)·W)
__global__ __launch_bounds__(256) void scatter_kernel(const int* __restrict__ ei,
                                                      const float* __restrict__ dinv,
                                                      const float* __restrict__ x,
                                                      float* __restrict__ acc, int E) {
    long long idx = (long long)blockIdx.x * 256 + threadIdx.x;
    int e = (int)(idx >> 6);
    if (e >= E) return;
    int lane = (int)(idx & 63);
    int s = ei[e];
    int d = ei[E + e];
    float w = dinv[s] * dinv[d];
    atomicAdd(&acc[(long long)d * DFEAT + lane],
              x[(long long)s * DFEAT + lane] * w);
}

// Fused epilogue, IN-PLACE on d_out: u = row @ W + b; expmap0 + proj; fp32 store.
// 4 nodes per 256-thread block; W staged in LDS (fp32, 16 KB). Row is fully read
// into LDS before any lane writes it back, so in-place is race-free.
__global__ __launch_bounds__(256) void out_kernel(float* __restrict__ io,
                                                  const float* __restrict__ W,
                                                  const float* __restrict__ b,
                                                  int n) {
    __shared__ float Wl[DFEAT * DFEAT];   // 16 KB
    __shared__ float xl[4][DFEAT];
    int t = threadIdx.x;
    for (int i = t; i < DFEAT * DFEAT; i += 256) Wl[i] = W[i];
    int r = t >> 6;       // node within block (0..3) == wave id
    int c = t & 63;       // output column == lane
    int node = blockIdx.x * 4 + r;
    if (node < n) xl[r][c] = io[(long long)node * DFEAT + c];
    __syncthreads();
    if (node >= n) return;

    float u = b[c];
    #pragma unroll
    for (int k = 0; k < DFEAT; ++k)
        u = fmaf(xl[r][k], Wl[k * DFEAT + c], u);

    // wave-wide sum of squares (row == wave, 64 lanes)
    float ss = u * u;
    #pragma unroll
    for (int off = 32; off > 0; off >>= 1) ss += __shfl_xor(ss, off, 64);
    float norm = fmaxf(sqrtf(ss), 1e-15f);
    float tn = tanhf(norm);                         // expmap0 magnitude (c=1)
    float scale = fminf(tn, 1.0f - 4e-3f) / norm;   // proj cap on result norm
    io[(long long)node * DFEAT + c] = u * scale;
}

// ---------------- launch ----------------

extern "C" void kernel_launch(void* const* d_in, const int* in_sizes, int n_in,
                              void* d_out, int out_size, void* d_ws, size_t ws_size,
                              hipStream_t stream) {
    const float* x = (const float*)d_in[0];
    const float* W = (const float*)d_in[1];
    const float* b = (const float*)d_in[2];
    const int* ei  = (const int*)d_in[3];

    int n  = in_sizes[0] / DFEAT;      // 100000
    int E  = in_sizes[3] / 2;          // 1200000
    int nd = n * DFEAT;

    float* deg = (float*)d_ws;         // n floats (0.5 MB)
    float* acc = (float*)d_out;        // accumulate directly in the output buffer

    init_kernel<<<(n + 255) / 256, 256, 0, stream>>>(deg, n);
    degree_kernel<<<(E + 255) / 256, 256, 0, stream>>>(ei, deg, E);
    dinv_kernel<<<(n + 255) / 256, 256, 0, stream>>>(deg, n);
    seed_kernel<<<(nd + 255) / 256, 256, 0, stream>>>(x, deg, acc, n);
    long long scatter_threads = (long long)E * DFEAT;
    scatter_kernel<<<(int)((scatter_threads + 255) / 256), 256, 0, stream>>>(ei, deg, x, acc, E);
    out_kernel<<<(n + 3) / 4, 256, 0, stream>>>(acc, W, b, n);
}

// Round 4
// 361.394 us; speedup vs baseline: 1.3304x; 1.3304x over previous
//
#include <hip/hip_runtime.h>
#include <hip/hip_bf16.h>

#define DFEAT 64

// ---------------- kernels ----------------

// cnt = 0
__global__ __launch_bounds__(256) void init_kernel(int* cnt, int n) {
    int i = blockIdx.x * blockDim.x + threadIdx.x;
    if (i < n) cnt[i] = 0;
}

// cnt[dst] += 1 per edge (int atomics)
__global__ __launch_bounds__(256) void degree_kernel(const int* __restrict__ ei, int* cnt, int E) {
    int e = blockIdx.x * blockDim.x + threadIdx.x;
    if (e < E) atomicAdd(&cnt[ei[E + e]], 1);
}

// ---- 3-kernel exclusive prefix scan over cnt[n] -> offsets[n] (+ total in offsets[n]) ----
// scanA: 1024 elements / block (256 thr x 4). Writes per-element block-local exclusive
// scan into offsets[], and block total into blocksum[].
__global__ __launch_bounds__(256) void scanA_kernel(const int* __restrict__ cnt,
                                                    int* __restrict__ offsets,
                                                    int* __restrict__ blocksum, int n) {
    __shared__ int lds[256];
    int t = threadIdx.x;
    int base = blockIdx.x * 1024;
    int v[4]; int s = 0;
    #pragma unroll
    for (int i = 0; i < 4; ++i) {
        int idx = base + t * 4 + i;
        v[i] = (idx < n) ? cnt[idx] : 0;
        s += v[i];
    }
    lds[t] = s;
    __syncthreads();
    // inclusive Hillis-Steele over 256 thread sums
    #pragma unroll
    for (int off = 1; off < 256; off <<= 1) {
        int y = (t >= off) ? lds[t - off] : 0;
        __syncthreads();
        lds[t] += y;
        __syncthreads();
    }
    int excl = lds[t] - s;   // thread-level exclusive
    int run = excl;
    #pragma unroll
    for (int i = 0; i < 4; ++i) {
        int idx = base + t * 4 + i;
        if (idx < n) offsets[idx] = run;
        run += v[i];
    }
    if (t == 255) blocksum[blockIdx.x] = lds[255];
}

// scanB: single block, exclusive scan of blocksum[nb] -> blockoff[nb]
__global__ __launch_bounds__(128) void scanB_kernel(const int* __restrict__ blocksum,
                                                    int* __restrict__ blockoff, int nb) {
    __shared__ int lds[128];
    int t = threadIdx.x;
    int s = (t < nb) ? blocksum[t] : 0;
    lds[t] = s;
    __syncthreads();
    #pragma unroll
    for (int off = 1; off < 128; off <<= 1) {
        int y = (t >= off) ? lds[t - off] : 0;
        __syncthreads();
        lds[t] += y;
        __syncthreads();
    }
    if (t < nb) blockoff[t] = lds[t] - s;
}

// scanC: finalize offsets, copy to cursor, dinv = rsqrt(cnt+1), offsets[n] = E
__global__ __launch_bounds__(256) void scanC_kernel(const int* __restrict__ cnt,
                                                    int* __restrict__ offsets,
                                                    int* __restrict__ cursor,
                                                    float* __restrict__ dinv,
                                                    const int* __restrict__ blockoff, int n) {
    int i = blockIdx.x * blockDim.x + threadIdx.x;
    if (i >= n) return;
    int off = offsets[i] + blockoff[i >> 10];
    offsets[i] = off;
    cursor[i] = off;
    dinv[i] = rsqrtf((float)(cnt[i] + 1));
    if (i == n - 1) offsets[n] = off + cnt[i];
}

// Bin edges by dst (counting sort, arbitrary intra-node order): srcs[pos] = src
__global__ __launch_bounds__(256) void bin_kernel(const int* __restrict__ ei,
                                                  int* __restrict__ cursor,
                                                  int* __restrict__ srcs, int E) {
    int e = blockIdx.x * blockDim.x + threadIdx.x;
    if (e >= E) return;
    int s = ei[e];
    int d = ei[E + e];
    int pos = atomicAdd(&cursor[d], 1);
    srcs[pos] = s;
}

// Fused: per-node register aggregation (self-loop + CSR neighbors) -> 64x64 GEMM
// (+bias) -> expmap0 -> proj -> fp32 store. One wave per node, 4 nodes/block.
__global__ __launch_bounds__(256) void agg_kernel(const int* __restrict__ offsets,
                                                  const int* __restrict__ srcs,
                                                  const float* __restrict__ dinv,
                                                  const float* __restrict__ x,
                                                  const float* __restrict__ W,
                                                  const float* __restrict__ b,
                                                  float* __restrict__ out, int n) {
    __shared__ float Wl[DFEAT * DFEAT];   // 16 KB
    __shared__ float xl[4][DFEAT];
    int t = threadIdx.x;
    // stage W (fp32, broadcast-reused by all blocks -> L2 resident)
    #pragma unroll
    for (int i = 0; i < 16; ++i) Wl[i * 256 + t] = W[i * 256 + t];
    __syncthreads();

    int r = t >> 6;        // wave id == node within block
    int lane = t & 63;     // feature index
    int node = blockIdx.x * 4 + r;

    float u = 0.0f;
    if (node < n) {
        float di = dinv[node];
        u = x[(long long)node * DFEAT + lane] * di * di;   // self-loop
        int beg = offsets[node];
        int end = offsets[node + 1];
        for (int base2 = beg; base2 < end; base2 += 64) {
            int m = end - base2; if (m > 64) m = 64;
            int sj = 0; float wj = 0.0f;
            if (lane < m) { sj = srcs[base2 + lane]; wj = dinv[sj]; }
            for (int j = 0; j < m; ++j) {
                int s   = __shfl(sj, j, 64);
                float w = __shfl(wj, j, 64);
                u = fmaf(x[(long long)s * DFEAT + lane], w * di, u);
            }
        }
        xl[r][lane] = u;
    }
    __syncthreads();
    if (node >= n) return;

    float o = b[lane];
    #pragma unroll
    for (int k = 0; k < DFEAT; ++k)
        o = fmaf(xl[r][k], Wl[k * DFEAT + lane], o);

    // wave-wide sum of squares
    float ss = o * o;
    #pragma unroll
    for (int off = 32; off > 0; off >>= 1) ss += __shfl_xor(ss, off, 64);
    float norm = fmaxf(sqrtf(ss), 1e-15f);
    float tn = tanhf(norm);                          // expmap0 magnitude (c=1)
    float scale = fminf(tn, 1.0f - 4e-3f) / norm;    // proj cap
    out[(long long)node * DFEAT + lane] = o * scale;
}

// ---------------- launch ----------------

extern "C" void kernel_launch(void* const* d_in, const int* in_sizes, int n_in,
                              void* d_out, int out_size, void* d_ws, size_t ws_size,
                              hipStream_t stream) {
    const float* x = (const float*)d_in[0];
    const float* W = (const float*)d_in[1];
    const float* b = (const float*)d_in[2];
    const int* ei  = (const int*)d_in[3];

    int n = in_sizes[0] / DFEAT;      // 100000
    int E = in_sizes[3] / 2;          // 1200000
    int nb = (n + 1023) / 1024;       // 98 scan blocks

    // workspace layout (4-byte units)
    int*   cnt      = (int*)d_ws;                 // n
    int*   offsets  = cnt + n;                    // n+1
    int*   cursor   = offsets + (n + 1);          // n
    float* dinv     = (float*)(cursor + n);       // n
    int*   blocksum = (int*)(dinv + n);           // 128
    int*   blockoff = blocksum + 128;             // 128
    int*   srcs     = blockoff + 128;             // E

    float* out = (float*)d_out;

    init_kernel  <<<(n + 255) / 256, 256, 0, stream>>>(cnt, n);
    degree_kernel<<<(E + 255) / 256, 256, 0, stream>>>(ei, cnt, E);
    scanA_kernel <<<nb, 256, 0, stream>>>(cnt, offsets, blocksum, n);
    scanB_kernel <<<1, 128, 0, stream>>>(blocksum, blockoff, nb);
    scanC_kernel <<<(n + 255) / 256, 256, 0, stream>>>(cnt, offsets, cursor, dinv, blockoff, n);
    bin_kernel   <<<(E + 255) / 256, 256, 0, stream>>>(ei, cursor, srcs, E);
    agg_kernel   <<<(n + 3) / 4, 256, 0, stream>>>(offsets, srcs, dinv, x, W, b, out, n);
}

// Round 5
// 324.564 us; speedup vs baseline: 1.4814x; 1.1135x over previous
//
#include <hip/hip_runtime.h>
#include <hip/hip_bf16.h>

#define DFEAT 64

// ---------------- kernels ----------------

// cnt = 0
__global__ __launch_bounds__(256) void init_kernel(int* cnt, int n) {
    int i = blockIdx.x * blockDim.x + threadIdx.x;
    if (i < n) cnt[i] = 0;
}

// cnt[dst] += 1 per edge (int atomics)
__global__ __launch_bounds__(256) void degree_kernel(const int* __restrict__ ei, int* cnt, int E) {
    int e = blockIdx.x * blockDim.x + threadIdx.x;
    if (e < E) atomicAdd(&cnt[ei[E + e]], 1);
}

// ---- exclusive prefix scan over PADDED per-node slot counts ----
// slots_i = (cnt_i + 2) & ~1  == pad(self + cnt_i) to even  (room for sentinel)
__global__ __launch_bounds__(256) void scanA_kernel(const int* __restrict__ cnt,
                                                    int* __restrict__ offsets,
                                                    int* __restrict__ blocksum, int n) {
    __shared__ int lds[256];
    int t = threadIdx.x;
    int base = blockIdx.x * 1024;
    int v[4]; int s = 0;
    #pragma unroll
    for (int i = 0; i < 4; ++i) {
        int idx = base + t * 4 + i;
        v[i] = (idx < n) ? ((cnt[idx] + 2) & ~1) : 0;
        s += v[i];
    }
    lds[t] = s;
    __syncthreads();
    #pragma unroll
    for (int off = 1; off < 256; off <<= 1) {
        int y = (t >= off) ? lds[t - off] : 0;
        __syncthreads();
        lds[t] += y;
        __syncthreads();
    }
    int run = lds[t] - s;
    #pragma unroll
    for (int i = 0; i < 4; ++i) {
        int idx = base + t * 4 + i;
        if (idx < n) offsets[idx] = run;
        run += v[i];
    }
    if (t == 255) blocksum[blockIdx.x] = lds[255];
}

// single block, exclusive scan of blocksum[nb]
__global__ __launch_bounds__(128) void scanB_kernel(const int* __restrict__ blocksum,
                                                    int* __restrict__ blockoff, int nb) {
    __shared__ int lds[128];
    int t = threadIdx.x;
    int s = (t < nb) ? blocksum[t] : 0;
    lds[t] = s;
    __syncthreads();
    #pragma unroll
    for (int off = 1; off < 128; off <<= 1) {
        int y = (t >= off) ? lds[t - off] : 0;
        __syncthreads();
        lds[t] += y;
        __syncthreads();
    }
    if (t < nb) blockoff[t] = lds[t] - s;
}

// finalize offsets; write self-loop slot + sentinel pad; cursor; dinv
__global__ __launch_bounds__(256) void scanC_kernel(const int* __restrict__ cnt,
                                                    int* __restrict__ offsets,
                                                    int* __restrict__ cursor,
                                                    float* __restrict__ dinv,
                                                    const int* __restrict__ blockoff,
                                                    int* __restrict__ srcs, int n) {
    int i = blockIdx.x * blockDim.x + threadIdx.x;
    if (i >= n) return;
    int off = offsets[i] + blockoff[i >> 10];
    offsets[i] = off;
    srcs[off] = i;           // self-loop occupies slot 0 of the segment
    cursor[i] = off + 1;
    int c = cnt[i];
    int total = c + 1;
    dinv[i] = rsqrtf((float)total);
    if (total & 1) srcs[off + total] = n;   // sentinel -> zero row
    if (i == n - 1) offsets[n] = off + ((c + 2) & ~1);
}

// xs[row] = bf16(x[row] * dinv[row]), packed 2 features/dword; row n = zeros
__global__ __launch_bounds__(256) void xsprep_kernel(const float* __restrict__ x,
                                                     const float* __restrict__ dinv,
                                                     unsigned* __restrict__ xs, int n) {
    int i = blockIdx.x * blockDim.x + threadIdx.x;   // dword index
    int total = (n + 1) * 32;
    if (i >= total) return;
    int row = i >> 5, col = i & 31;
    unsigned v = 0;
    if (row < n) {
        float di = dinv[row];
        float f0 = x[row * DFEAT + 2 * col] * di;
        float f1 = x[row * DFEAT + 2 * col + 1] * di;
        unsigned u0 = __float_as_uint(f0); u0 = (u0 + 0x7fffu + ((u0 >> 16) & 1u)) >> 16;
        unsigned u1 = __float_as_uint(f1); u1 = (u1 + 0x7fffu + ((u1 >> 16) & 1u)) >> 16;
        v = (u0 & 0xffffu) | (u1 << 16);
    }
    xs[i] = v;
}

// Bin edges by dst (counting sort): srcs[pos] = src
__global__ __launch_bounds__(256) void bin_kernel(const int* __restrict__ ei,
                                                  int* __restrict__ cursor,
                                                  int* __restrict__ srcs, int E) {
    int e = blockIdx.x * blockDim.x + threadIdx.x;
    if (e >= E) return;
    int s = ei[e];
    int d = ei[E + e];
    int pos = atomicAdd(&cursor[d], 1);
    srcs[pos] = s;
}

// Fused: bf16 row-sum gather (2 edges per iteration, half-wave each) -> *dinv ->
// 64x64 GEMM (+bias) -> expmap0 -> proj -> fp32 store. One wave per node.
__global__ __launch_bounds__(256) void agg_kernel(const int* __restrict__ offsets,
                                                  const int* __restrict__ srcs,
                                                  const float* __restrict__ dinv,
                                                  const unsigned* __restrict__ xs,
                                                  const float* __restrict__ W,
                                                  const float* __restrict__ b,
                                                  float* __restrict__ out, int n) {
    __shared__ float Wl[DFEAT * DFEAT];   // 16 KB
    __shared__ float xl[4][DFEAT];
    int t = threadIdx.x;
    #pragma unroll
    for (int i = 0; i < 16; ++i) Wl[i * 256 + t] = W[i * 256 + t];

    int r = t >> 6;          // wave id == node within block
    int lane = t & 63;
    int half = lane >> 5;    // which edge of the pair this half-wave gathers
    int col = lane & 31;     // dword column (features 2*col, 2*col+1)
    int node = blockIdx.x * 4 + r;

    if (node < n) {
        float ux = 0.0f, uy = 0.0f;
        int beg = offsets[node];
        int end = offsets[node + 1];       // segment length is even
        for (int base = beg; base < end; base += 64) {
            int m = end - base; if (m > 64) m = 64;   // even
            int idx = 0;
            if (lane < m) idx = srcs[base + lane];
            int pairs = m >> 1;
            for (int j = 0; j < pairs; ++j) {
                int s = __shfl(idx, 2 * j + half, 64);
                unsigned d = xs[(unsigned)s * 32 + col];
                ux += __uint_as_float(d << 16);
                uy += __uint_as_float(d & 0xffff0000u);
            }
        }
        // fold the two half-wave partial sums
        ux += __shfl_xor(ux, 32, 64);
        uy += __shfl_xor(uy, 32, 64);
        if (half == 0) {
            float di = dinv[node];
            xl[r][2 * col]     = ux * di;
            xl[r][2 * col + 1] = uy * di;
        }
    }
    __syncthreads();
    if (node >= n) return;

    float o = b[lane];
    #pragma unroll
    for (int k = 0; k < DFEAT; ++k)
        o = fmaf(xl[r][k], Wl[k * DFEAT + lane], o);

    float ss = o * o;
    #pragma unroll
    for (int off = 32; off > 0; off >>= 1) ss += __shfl_xor(ss, off, 64);
    float norm = fmaxf(sqrtf(ss), 1e-15f);
    float tn = tanhf(norm);                          // expmap0 magnitude (c=1)
    float scale = fminf(tn, 1.0f - 4e-3f) / norm;    // proj cap
    out[(long long)node * DFEAT + lane] = o * scale;
}

// ---------------- launch ----------------

extern "C" void kernel_launch(void* const* d_in, const int* in_sizes, int n_in,
                              void* d_out, int out_size, void* d_ws, size_t ws_size,
                              hipStream_t stream) {
    const float* x = (const float*)d_in[0];
    const float* W = (const float*)d_in[1];
    const float* b = (const float*)d_in[2];
    const int* ei  = (const int*)d_in[3];

    int n = in_sizes[0] / DFEAT;      // 100000
    int E = in_sizes[3] / 2;          // 1200000
    int nb = (n + 1023) / 1024;       // scan blocks (<=128)

    // workspace layout (4-byte units): ~21 MB total
    int*      cnt      = (int*)d_ws;                 // n
    int*      offsets  = cnt + n;                    // n+1
    int*      cursor   = offsets + (n + 1);          // n
    float*    dinv     = (float*)(cursor + n);       // n
    int*      blocksum = (int*)(dinv + n);           // 128
    int*      blockoff = blocksum + 128;             // 128
    int*      srcs     = blockoff + 128;             // E + 2n + slack
    unsigned* xs       = (unsigned*)(srcs + E + 2 * n + 64);   // (n+1)*32

    float* out = (float*)d_out;

    init_kernel  <<<(n + 255) / 256, 256, 0, stream>>>(cnt, n);
    degree_kernel<<<(E + 255) / 256, 256, 0, stream>>>(ei, cnt, E);
    scanA_kernel <<<nb, 256, 0, stream>>>(cnt, offsets, blocksum, n);
    scanB_kernel <<<1, 128, 0, stream>>>(blocksum, blockoff, nb);
    scanC_kernel <<<(n + 255) / 256, 256, 0, stream>>>(cnt, offsets, cursor, dinv, blockoff, srcs, n);
    xsprep_kernel<<<((n + 1) * 32 + 255) / 256, 256, 0, stream>>>(x, dinv, xs, n);
    bin_kernel   <<<(E + 255) / 256, 256, 0, stream>>>(ei, cursor, srcs, E);
    agg_kernel   <<<(n + 3) / 4, 256, 0, stream>>>(offsets, srcs, dinv, xs, W, b, out, n);
}

// Round 6
// 235.428 us; speedup vs baseline: 2.0422x; 1.3786x over previous
//
#include <hip/hip_runtime.h>
#include <hip/hip_bf16.h>

#define DFEAT 64
#define NBSH  8        // bucket = dst >> 8  (256 nodes per bucket)
#define NPB   256      // nodes per bucket
#define EPB   8192     // edges per partition block

// ---- A: per-block bucket histogram (LDS) ----
__global__ __launch_bounds__(256) void histA_kernel(const int* __restrict__ ei,
                                                    int* __restrict__ blkhist, int E) {
    __shared__ int h[512];
    int t = threadIdx.x;
    h[t] = 0; h[t + 256] = 0;
    __syncthreads();
    int base = blockIdx.x * EPB;
    #pragma unroll
    for (int i = 0; i < EPB / 256; ++i) {
        int e = base + i * 256 + t;
        if (e < E) atomicAdd(&h[ei[E + e] >> NBSH], 1);
    }
    __syncthreads();
    blkhist[blockIdx.x * 512 + t]       = h[t];
    blkhist[blockIdx.x * 512 + t + 256] = h[t + 256];
}

// ---- B: in-place per-(block,bucket) bases + bucket exclusive scan ----
__global__ __launch_bounds__(512) void scanB_kernel(int* __restrict__ blkhist,
                                                    int* __restrict__ bucketbase, int nblk) {
    __shared__ int lds[512];
    int t = threadIdx.x;
    int run = 0;
    for (int blk = 0; blk < nblk; ++blk) {
        int idx = blk * 512 + t;
        int v = blkhist[idx];
        blkhist[idx] = run;      // block-local base within bucket t
        run += v;
    }
    lds[t] = run;                // bucket total
    __syncthreads();
    int s = run;
    for (int off = 1; off < 512; off <<= 1) {
        int y = (t >= off) ? lds[t - off] : 0;
        __syncthreads();
        lds[t] += y;
        __syncthreads();
    }
    bucketbase[t] = lds[t] - s;  // exclusive; t>NB entries harmless (=E)
}

// ---- C: partition edges into buckets; pack (dst&255)<<17 | src (4B/edge) ----
__global__ __launch_bounds__(256) void partC_kernel(const int* __restrict__ ei,
                                                    const int* __restrict__ blkhist,
                                                    const int* __restrict__ bucketbase,
                                                    unsigned* __restrict__ ebuf, int E) {
    __shared__ int cur[512];
    int t = threadIdx.x;
    cur[t]       = bucketbase[t]       + blkhist[blockIdx.x * 512 + t];
    cur[t + 256] = bucketbase[t + 256] + blkhist[blockIdx.x * 512 + t + 256];
    __syncthreads();
    int base = blockIdx.x * EPB;
    #pragma unroll
    for (int i = 0; i < EPB / 256; ++i) {
        int e = base + i * 256 + t;
        if (e < E) {
            int s = ei[e];
            int d = ei[E + e];
            int pos = atomicAdd(&cur[d >> NBSH], 1);
            ebuf[pos] = (unsigned)s | ((unsigned)(d & (NPB - 1)) << 17);
        }
    }
}

// ---- D: per-bucket CSR build in LDS (single-writer srcs region) ----
// Segment layout per node: [self][edges...][sentinels to pad len to x4]
__global__ __launch_bounds__(256) void csrD_kernel(const unsigned* __restrict__ ebuf,
                                                   const int* __restrict__ bucketbase,
                                                   int* __restrict__ srcs,
                                                   int* __restrict__ begs,
                                                   int* __restrict__ lens,
                                                   float* __restrict__ dinv, int n) {
    __shared__ int cnt[256];
    __shared__ int tmp[256];
    int t = threadIdx.x;
    int b = blockIdx.x;
    int ebeg = bucketbase[b], eend = bucketbase[b + 1];
    int regionbase = ebeg + b * (4 * NPB);     // +4 pad slots per node
    cnt[t] = 0;
    __syncthreads();
    for (int e = ebeg + t; e < eend; e += 256)
        atomicAdd(&cnt[ebuf[e] >> 17], 1);
    __syncthreads();
    int nid = (b << NBSH) + t;
    int deg = cnt[t];
    int slots = (nid < n) ? ((deg + 4) & ~3) : 0;
    tmp[t] = slots;
    __syncthreads();
    int s = slots;
    for (int o = 1; o < 256; o <<= 1) {
        int y = (t >= o) ? tmp[t - o] : 0;
        __syncthreads();
        tmp[t] += y;
        __syncthreads();
    }
    int excl = tmp[t] - s;
    if (nid < n) {
        int beg_abs = regionbase + excl;
        begs[nid] = beg_abs;
        lens[nid] = slots;
        dinv[nid] = rsqrtf((float)(deg + 1));
        srcs[beg_abs] = nid;                            // self-loop slot
        for (int k = deg + 1; k < slots; ++k) srcs[beg_abs + k] = n;  // sentinels
    }
    cnt[t] = excl + 1;                                  // cursor past self slot
    __syncthreads();
    for (int e = ebeg + t; e < eend; e += 256) {
        unsigned v = ebuf[e];
        int pos = atomicAdd(&cnt[v >> 17], 1);
        srcs[regionbase + pos] = (int)(v & 0x1ffffu);
    }
}

// ---- xs[row] = bf16(x[row] * dinv[row]) packed 2/dword; row n = zeros ----
__global__ __launch_bounds__(256) void xsprep_kernel(const float* __restrict__ x,
                                                     const float* __restrict__ dinv,
                                                     unsigned* __restrict__ xs, int n) {
    int i = blockIdx.x * blockDim.x + threadIdx.x;
    int total = (n + 1) * 32;
    if (i >= total) return;
    int row = i >> 5, col = i & 31;
    unsigned v = 0;
    if (row < n) {
        float di = dinv[row];
        float f0 = x[row * DFEAT + 2 * col] * di;
        float f1 = x[row * DFEAT + 2 * col + 1] * di;
        unsigned u0 = __float_as_uint(f0); u0 = (u0 + 0x7fffu + ((u0 >> 16) & 1u)) >> 16;
        unsigned u1 = __float_as_uint(f1); u1 = (u1 + 0x7fffu + ((u1 >> 16) & 1u)) >> 16;
        v = (u0 & 0xffffu) | (u1 << 16);
    }
    xs[i] = v;
}

// ---- Fused gather(4 edges/iter, uint2 loads) -> GEMM(+bias) -> expmap0 -> proj ----
__global__ __launch_bounds__(256) void agg_kernel(const int* __restrict__ begs,
                                                  const int* __restrict__ lens,
                                                  const int* __restrict__ srcs,
                                                  const float* __restrict__ dinv,
                                                  const uint2* __restrict__ xs2,
                                                  const float* __restrict__ W,
                                                  const float* __restrict__ b,
                                                  float* __restrict__ out, int n) {
    __shared__ float Wl[DFEAT * DFEAT];   // 16 KB
    __shared__ float xl[4][DFEAT];
    int t = threadIdx.x;
    #pragma unroll
    for (int i = 0; i < 16; ++i) Wl[i * 256 + t] = W[i * 256 + t];

    int r = t >> 6, lane = t & 63;
    int g = lane >> 4;        // edge group (0..3)
    int q = lane & 15;        // uint2 column -> features 4q..4q+3
    int node = blockIdx.x * 4 + r;

    if (node < n) {
        float f0 = 0, f1 = 0, f2 = 0, f3 = 0;
        int beg = begs[node];
        int end = beg + lens[node];            // multiple of 4
        for (int base = beg; base < end; base += 64) {
            int m = end - base; if (m > 64) m = 64;   // multiple of 4
            int idx = 0;
            if (lane < m) idx = srcs[base + lane];
            int quads = m >> 2;
            for (int j = 0; j < quads; ++j) {
                int sv = __shfl(idx, 4 * j + g, 64);
                uint2 d = xs2[(unsigned)sv * 16 + q];
                f0 += __uint_as_float(d.x << 16);
                f1 += __uint_as_float(d.x & 0xffff0000u);
                f2 += __uint_as_float(d.y << 16);
                f3 += __uint_as_float(d.y & 0xffff0000u);
            }
        }
        #pragma unroll
        for (int off = 16; off < 64; off <<= 1) {
            f0 += __shfl_xor(f0, off, 64);
            f1 += __shfl_xor(f1, off, 64);
            f2 += __shfl_xor(f2, off, 64);
            f3 += __shfl_xor(f3, off, 64);
        }
        if (g == 0) {
            float di = dinv[node];
            xl[r][4 * q + 0] = f0 * di;
            xl[r][4 * q + 1] = f1 * di;
            xl[r][4 * q + 2] = f2 * di;
            xl[r][4 * q + 3] = f3 * di;
        }
    }
    __syncthreads();
    if (node >= n) return;

    float o = b[lane];
    #pragma unroll
    for (int k = 0; k < DFEAT; ++k)
        o = fmaf(xl[r][k], Wl[k * DFEAT + lane], o);

    float ss = o * o;
    #pragma unroll
    for (int off = 32; off > 0; off >>= 1) ss += __shfl_xor(ss, off, 64);
    float norm = fmaxf(sqrtf(ss), 1e-15f);
    float tn = tanhf(norm);                          // expmap0 magnitude (c=1)
    float scale = fminf(tn, 1.0f - 4e-3f) / norm;    // proj cap
    out[(long long)node * DFEAT + lane] = o * scale;
}

// ---------------- launch ----------------

extern "C" void kernel_launch(void* const* d_in, const int* in_sizes, int n_in,
                              void* d_out, int out_size, void* d_ws, size_t ws_size,
                              hipStream_t stream) {
    const float* x = (const float*)d_in[0];
    const float* W = (const float*)d_in[1];
    const float* b = (const float*)d_in[2];
    const int* ei  = (const int*)d_in[3];

    int n = in_sizes[0] / DFEAT;           // 100000
    int E = in_sizes[3] / 2;               // 1200000
    int NB = (n + NPB - 1) / NPB;          // 391 buckets
    int nblk = (E + EPB - 1) / EPB;        // 147 partition blocks

    // workspace layout (ints): ~20.8 MB
    int* blkhist    = (int*)d_ws;                          // nblk*512
    int* bucketbase = blkhist + nblk * 512;                // 512
    int* srcs       = bucketbase + 512;                    // E + NB*4*NPB
    int* begs       = srcs + E + NB * 4 * NPB;             // n
    int* lens       = begs + n;                            // n
    float* dinv     = (float*)(lens + n);                  // n
    unsigned* ebuf  = (unsigned*)(dinv + n);               // union: E (ebuf) then (n+1)*32 (xs)
    unsigned* xs    = ebuf;                                // xs overlays ebuf (ebuf dead after csrD)

    float* out = (float*)d_out;

    histA_kernel <<<nblk, 256, 0, stream>>>(ei, blkhist, E);
    scanB_kernel <<<1, 512, 0, stream>>>(blkhist, bucketbase, nblk);
    partC_kernel <<<nblk, 256, 0, stream>>>(ei, blkhist, bucketbase, ebuf, E);
    csrD_kernel  <<<NB, 256, 0, stream>>>(ebuf, bucketbase, srcs, begs, lens, dinv, n);
    xsprep_kernel<<<((n + 1) * 32 + 255) / 256, 256, 0, stream>>>(x, dinv, xs, n);
    agg_kernel   <<<(n + 3) / 4, 256, 0, stream>>>(begs, lens, srcs, dinv,
                                                   (const uint2*)xs, W, b, out, n);
}

// Round 7
// 225.643 us; speedup vs baseline: 2.1308x; 1.0434x over previous
//
#include <hip/hip_runtime.h>
#include <hip/hip_bf16.h>

#define DFEAT 64
#define NBSH  8        // bucket = dst >> 8  (256 nodes per bucket)
#define NPB   256      // nodes per bucket
#define EPB   8192     // edges per partition block

// ---- A: per-block bucket histogram (LDS) ----
__global__ __launch_bounds__(256) void histA_kernel(const int* __restrict__ ei,
                                                    int* __restrict__ blkhist, int E) {
    __shared__ int h[512];
    int t = threadIdx.x;
    h[t] = 0; h[t + 256] = 0;
    __syncthreads();
    int base = blockIdx.x * EPB;
    #pragma unroll
    for (int i = 0; i < EPB / 256; ++i) {
        int e = base + i * 256 + t;
        if (e < E) atomicAdd(&h[ei[E + e] >> NBSH], 1);
    }
    __syncthreads();
    blkhist[blockIdx.x * 512 + t]       = h[t];
    blkhist[blockIdx.x * 512 + t + 256] = h[t + 256];
}

// ---- B: in-place per-(block,bucket) bases + bucket exclusive scan ----
__global__ __launch_bounds__(512) void scanB_kernel(int* __restrict__ blkhist,
                                                    int* __restrict__ bucketbase, int nblk) {
    __shared__ int lds[512];
    int t = threadIdx.x;
    int run = 0;
    for (int blk = 0; blk < nblk; ++blk) {
        int idx = blk * 512 + t;
        int v = blkhist[idx];
        blkhist[idx] = run;      // block-local base within bucket t
        run += v;
    }
    lds[t] = run;                // bucket total
    __syncthreads();
    int s = run;
    for (int off = 1; off < 512; off <<= 1) {
        int y = (t >= off) ? lds[t - off] : 0;
        __syncthreads();
        lds[t] += y;
        __syncthreads();
    }
    bucketbase[t] = lds[t] - s;  // exclusive; t>NB entries harmless (=E)
}

// ---- C: partition edges into buckets; pack (dst&255)<<17 | src (4B/edge) ----
__global__ __launch_bounds__(256) void partC_kernel(const int* __restrict__ ei,
                                                    const int* __restrict__ blkhist,
                                                    const int* __restrict__ bucketbase,
                                                    unsigned* __restrict__ ebuf, int E) {
    __shared__ int cur[512];
    int t = threadIdx.x;
    cur[t]       = bucketbase[t]       + blkhist[blockIdx.x * 512 + t];
    cur[t + 256] = bucketbase[t + 256] + blkhist[blockIdx.x * 512 + t + 256];
    __syncthreads();
    int base = blockIdx.x * EPB;
    #pragma unroll
    for (int i = 0; i < EPB / 256; ++i) {
        int e = base + i * 256 + t;
        if (e < E) {
            int s = ei[e];
            int d = ei[E + e];
            int pos = atomicAdd(&cur[d >> NBSH], 1);
            ebuf[pos] = (unsigned)s | ((unsigned)(d & (NPB - 1)) << 17);
        }
    }
}

// ---- D: per-bucket CSR build in LDS (single-writer srcs region) ----
// Segment layout per node: [self][edges...][sentinels to pad len to x4]
__global__ __launch_bounds__(256) void csrD_kernel(const unsigned* __restrict__ ebuf,
                                                   const int* __restrict__ bucketbase,
                                                   int* __restrict__ srcs,
                                                   int* __restrict__ begs,
                                                   int* __restrict__ lens,
                                                   float* __restrict__ dinv, int n) {
    __shared__ int cnt[256];
    __shared__ int tmp[256];
    int t = threadIdx.x;
    int b = blockIdx.x;
    int ebeg = bucketbase[b], eend = bucketbase[b + 1];
    int regionbase = ebeg + b * (4 * NPB);     // +4 pad slots per node
    cnt[t] = 0;
    __syncthreads();
    for (int e = ebeg + t; e < eend; e += 256)
        atomicAdd(&cnt[ebuf[e] >> 17], 1);
    __syncthreads();
    int nid = (b << NBSH) + t;
    int deg = cnt[t];
    int slots = (nid < n) ? ((deg + 4) & ~3) : 0;
    tmp[t] = slots;
    __syncthreads();
    int s = slots;
    for (int o = 1; o < 256; o <<= 1) {
        int y = (t >= o) ? tmp[t - o] : 0;
        __syncthreads();
        tmp[t] += y;
        __syncthreads();
    }
    int excl = tmp[t] - s;
    if (nid < n) {
        int beg_abs = regionbase + excl;
        begs[nid] = beg_abs;
        lens[nid] = slots;
        dinv[nid] = rsqrtf((float)(deg + 1));
        srcs[beg_abs] = nid;                            // self-loop slot
        for (int k = deg + 1; k < slots; ++k) srcs[beg_abs + k] = n;  // sentinels
    }
    cnt[t] = excl + 1;                                  // cursor past self slot
    __syncthreads();
    for (int e = ebeg + t; e < eend; e += 256) {
        unsigned v = ebuf[e];
        int pos = atomicAdd(&cnt[v >> 17], 1);
        srcs[regionbase + pos] = (int)(v & 0x1ffffu);
    }
}

// ---- xs[row] = bf16(x[row] * dinv[row]) packed 2/dword; row n = zeros ----
__global__ __launch_bounds__(256) void xsprep_kernel(const float* __restrict__ x,
                                                     const float* __restrict__ dinv,
                                                     unsigned* __restrict__ xs, int n) {
    int i = blockIdx.x * blockDim.x + threadIdx.x;
    int total = (n + 1) * 32;
    if (i >= total) return;
    int row = i >> 5, col = i & 31;
    unsigned v = 0;
    if (row < n) {
        float di = dinv[row];
        float f0 = x[row * DFEAT + 2 * col] * di;
        float f1 = x[row * DFEAT + 2 * col + 1] * di;
        unsigned u0 = __float_as_uint(f0); u0 = (u0 + 0x7fffu + ((u0 >> 16) & 1u)) >> 16;
        unsigned u1 = __float_as_uint(f1); u1 = (u1 + 0x7fffu + ((u1 >> 16) & 1u)) >> 16;
        v = (u0 & 0xffffu) | (u1 << 16);
    }
    xs[i] = v;
}

// ---- Persistent fused gather -> GEMM(+bias) -> expmap0 -> proj ----
// W staged ONCE per block; grid-stride over node-quads; no barriers in the loop
// (each wave's xl row is private to that wave -> wave-synchronous LDS).
__global__ __launch_bounds__(256) void agg_kernel(const int* __restrict__ begs,
                                                  const int* __restrict__ lens,
                                                  const int* __restrict__ srcs,
                                                  const float* __restrict__ dinv,
                                                  const uint2* __restrict__ xs2,
                                                  const float* __restrict__ W,
                                                  const float* __restrict__ b,
                                                  float* __restrict__ out,
                                                  int n, int nquads) {
    __shared__ float Wl[DFEAT * DFEAT];   // 16 KB
    __shared__ float xl[4][DFEAT];
    int t = threadIdx.x;
    #pragma unroll
    for (int i = 0; i < 16; ++i) Wl[i * 256 + t] = W[i * 256 + t];
    __syncthreads();   // the ONLY barrier

    int r = t >> 6, lane = t & 63;
    int g = lane >> 4;        // edge group (0..3)
    int q = lane & 15;        // uint2 column -> features 4q..4q+3
    float bias = b[lane];

    for (int quad = blockIdx.x; quad < nquads; quad += gridDim.x) {
        int node = quad * 4 + r;
        if (node >= n) continue;

        float f0 = 0, f1 = 0, f2 = 0, f3 = 0;
        int beg = begs[node];
        int end = beg + lens[node];            // multiple of 4
        for (int base = beg; base < end; base += 64) {
            int m = end - base; if (m > 64) m = 64;   // multiple of 4
            int idx = 0;
            if (lane < m) idx = srcs[base + lane];
            int quads_ = m >> 2;
            for (int j = 0; j < quads_; ++j) {
                int sv = __shfl(idx, 4 * j + g, 64);
                uint2 d = xs2[(unsigned)sv * 16 + q];
                f0 += __uint_as_float(d.x << 16);
                f1 += __uint_as_float(d.x & 0xffff0000u);
                f2 += __uint_as_float(d.y << 16);
                f3 += __uint_as_float(d.y & 0xffff0000u);
            }
        }
        #pragma unroll
        for (int off = 16; off < 64; off <<= 1) {
            f0 += __shfl_xor(f0, off, 64);
            f1 += __shfl_xor(f1, off, 64);
            f2 += __shfl_xor(f2, off, 64);
            f3 += __shfl_xor(f3, off, 64);
        }
        if (g == 0) {
            float di = dinv[node];
            xl[r][4 * q + 0] = f0 * di;
            xl[r][4 * q + 1] = f1 * di;
            xl[r][4 * q + 2] = f2 * di;
            xl[r][4 * q + 3] = f3 * di;
        }
        // wave-synchronous: same wave wrote xl[r], same wave reads it (lgkmcnt-ordered)

        float o0 = bias, o1 = 0.0f;   // 2 accumulators: halve the fma dep-chain
        #pragma unroll
        for (int k = 0; k < DFEAT; k += 2) {
            o0 = fmaf(xl[r][k],     Wl[k * DFEAT + lane],       o0);
            o1 = fmaf(xl[r][k + 1], Wl[(k + 1) * DFEAT + lane], o1);
        }
        float o = o0 + o1;

        float ss = o * o;
        #pragma unroll
        for (int off = 32; off > 0; off >>= 1) ss += __shfl_xor(ss, off, 64);
        float norm = fmaxf(sqrtf(ss), 1e-15f);
        float tn = tanhf(norm);                          // expmap0 magnitude (c=1)
        float scale = fminf(tn, 1.0f - 4e-3f) / norm;    // proj cap
        out[(long long)node * DFEAT + lane] = o * scale;
    }
}

// ---------------- launch ----------------

extern "C" void kernel_launch(void* const* d_in, const int* in_sizes, int n_in,
                              void* d_out, int out_size, void* d_ws, size_t ws_size,
                              hipStream_t stream) {
    const float* x = (const float*)d_in[0];
    const float* W = (const float*)d_in[1];
    const float* b = (const float*)d_in[2];
    const int* ei  = (const int*)d_in[3];

    int n = in_sizes[0] / DFEAT;           // 100000
    int E = in_sizes[3] / 2;               // 1200000
    int NB = (n + NPB - 1) / NPB;          // 391 buckets
    int nblk = (E + EPB - 1) / EPB;        // 147 partition blocks
    int nquads = (n + 3) / 4;              // 25000

    // workspace layout (ints): ~20.8 MB
    int* blkhist    = (int*)d_ws;                          // nblk*512
    int* bucketbase = blkhist + nblk * 512;                // 512
    int* srcs       = bucketbase + 512;                    // E + NB*4*NPB
    int* begs       = srcs + E + NB * 4 * NPB;             // n
    int* lens       = begs + n;                            // n
    float* dinv     = (float*)(lens + n);                  // n
    unsigned* ebuf  = (unsigned*)(dinv + n);               // union: E (ebuf) then (n+1)*32 (xs)
    unsigned* xs    = ebuf;                                // xs overlays ebuf (ebuf dead after csrD)

    float* out = (float*)d_out;

    int aggblocks = 2048;                  // 8 blocks/CU (LDS-limited residency)
    if (aggblocks > nquads) aggblocks = nquads;

    histA_kernel <<<nblk, 256, 0, stream>>>(ei, blkhist, E);
    scanB_kernel <<<1, 512, 0, stream>>>(blkhist, bucketbase, nblk);
    partC_kernel <<<nblk, 256, 0, stream>>>(ei, blkhist, bucketbase, ebuf, E);
    csrD_kernel  <<<NB, 256, 0, stream>>>(ebuf, bucketbase, srcs, begs, lens, dinv, n);
    xsprep_kernel<<<((n + 1) * 32 + 255) / 256, 256, 0, stream>>>(x, dinv, xs, n);
    agg_kernel   <<<aggblocks, 256, 0, stream>>>(begs, lens, srcs, dinv,
                                                 (const uint2*)xs, W, b, out, n, nquads);
}

// Round 8
// 195.440 us; speedup vs baseline: 2.4601x; 1.1545x over previous
//
#include <hip/hip_runtime.h>
#include <hip/hip_bf16.h>

#define DFEAT 64
#define NBSH  8        // bucket = dst >> 8  (256 nodes per bucket)
#define NPB   256      // nodes per bucket
#define EPB   8192     // edges per partition block

// ---- A: per-block bucket histogram (LDS); blkhistT layout [bucket][block] ----
__global__ __launch_bounds__(256) void histA_kernel(const int* __restrict__ ei,
                                                    int* __restrict__ blkhistT,
                                                    int E, int nblk) {
    __shared__ int h[512];
    int t = threadIdx.x;
    h[t] = 0; h[t + 256] = 0;
    __syncthreads();
    int base = blockIdx.x * EPB;
    #pragma unroll
    for (int i = 0; i < EPB / 256; ++i) {
        int e = base + i * 256 + t;
        if (e < E) atomicAdd(&h[ei[E + e] >> NBSH], 1);
    }
    __syncthreads();
    blkhistT[t * nblk + blockIdx.x]         = h[t];
    blkhistT[(t + 256) * nblk + blockIdx.x] = h[t + 256];
}

// ---- B1: per-bucket exclusive scan over blocks (512 blocks, contiguous rows) ----
__global__ __launch_bounds__(256) void scanB1_kernel(int* __restrict__ blkhistT,
                                                     int* __restrict__ buckettotal, int nblk) {
    __shared__ int lds[256];
    int t = threadIdx.x;
    int b = blockIdx.x;
    int v = (t < nblk) ? blkhistT[b * nblk + t] : 0;
    lds[t] = v;
    __syncthreads();
    #pragma unroll
    for (int off = 1; off < 256; off <<= 1) {
        int y = (t >= off) ? lds[t - off] : 0;
        __syncthreads();
        lds[t] += y;
        __syncthreads();
    }
    if (t < nblk) blkhistT[b * nblk + t] = lds[t] - v;   // block-local base
    if (t == 255) buckettotal[b] = lds[255];
}

// ---- B2: single block, exclusive scan of 512 bucket totals ----
__global__ __launch_bounds__(512) void scanB2_kernel(const int* __restrict__ buckettotal,
                                                     int* __restrict__ bucketbase) {
    __shared__ int lds[512];
    int t = threadIdx.x;
    int s = buckettotal[t];
    lds[t] = s;
    __syncthreads();
    #pragma unroll
    for (int off = 1; off < 512; off <<= 1) {
        int y = (t >= off) ? lds[t - off] : 0;
        __syncthreads();
        lds[t] += y;
        __syncthreads();
    }
    bucketbase[t] = lds[t] - s;
    if (t == 511) bucketbase[512] = lds[511];
}

// ---- C: partition edges into buckets; pack (dst&255)<<17 | src (4B/edge) ----
__global__ __launch_bounds__(256) void partC_kernel(const int* __restrict__ ei,
                                                    const int* __restrict__ blkhistT,
                                                    const int* __restrict__ bucketbase,
                                                    unsigned* __restrict__ ebuf, int E, int nblk) {
    __shared__ int cur[512];
    int t = threadIdx.x;
    cur[t]       = bucketbase[t]       + blkhistT[t * nblk + blockIdx.x];
    cur[t + 256] = bucketbase[t + 256] + blkhistT[(t + 256) * nblk + blockIdx.x];
    __syncthreads();
    int base = blockIdx.x * EPB;
    #pragma unroll
    for (int i = 0; i < EPB / 256; ++i) {
        int e = base + i * 256 + t;
        if (e < E) {
            int s = ei[e];
            int d = ei[E + e];
            int pos = atomicAdd(&cur[d >> NBSH], 1);
            ebuf[pos] = (unsigned)s | ((unsigned)(d & (NPB - 1)) << 17);
        }
    }
}

// ---- D: per-bucket CSR build in LDS (single-writer srcs region) ----
__global__ __launch_bounds__(256) void csrD_kernel(const unsigned* __restrict__ ebuf,
                                                   const int* __restrict__ bucketbase,
                                                   int* __restrict__ srcs,
                                                   int* __restrict__ begs,
                                                   int* __restrict__ lens,
                                                   float* __restrict__ dinv, int n) {
    __shared__ int cnt[256];
    __shared__ int tmp[256];
    int t = threadIdx.x;
    int b = blockIdx.x;
    int ebeg = bucketbase[b], eend = bucketbase[b + 1];
    int regionbase = ebeg + b * (4 * NPB);     // +4 pad slots per node
    cnt[t] = 0;
    __syncthreads();
    for (int e = ebeg + t; e < eend; e += 256)
        atomicAdd(&cnt[ebuf[e] >> 17], 1);
    __syncthreads();
    int nid = (b << NBSH) + t;
    int deg = cnt[t];
    int slots = (nid < n) ? ((deg + 4) & ~3) : 0;
    tmp[t] = slots;
    __syncthreads();
    int s = slots;
    for (int o = 1; o < 256; o <<= 1) {
        int y = (t >= o) ? tmp[t - o] : 0;
        __syncthreads();
        tmp[t] += y;
        __syncthreads();
    }
    int excl = tmp[t] - s;
    if (nid < n) {
        int beg_abs = regionbase + excl;
        begs[nid] = beg_abs;
        lens[nid] = slots;
        dinv[nid] = rsqrtf((float)(deg + 1));
        srcs[beg_abs] = nid;                            // self-loop slot
        for (int k = deg + 1; k < slots; ++k) srcs[beg_abs + k] = n;  // sentinels
    }
    cnt[t] = excl + 1;                                  // cursor past self slot
    __syncthreads();
    for (int e = ebeg + t; e < eend; e += 256) {
        unsigned v = ebuf[e];
        int pos = atomicAdd(&cnt[v >> 17], 1);
        srcs[regionbase + pos] = (int)(v & 0x1ffffu);
    }
}

// ---- xs[row] = bf16(x[row] * dinv[row]) packed 2/dword; row n = zeros ----
__global__ __launch_bounds__(256) void xsprep_kernel(const float* __restrict__ x,
                                                     const float* __restrict__ dinv,
                                                     unsigned* __restrict__ xs, int n) {
    int i = blockIdx.x * blockDim.x + threadIdx.x;
    int total = (n + 1) * 32;
    if (i >= total) return;
    int row = i >> 5, col = i & 31;
    unsigned v = 0;
    if (row < n) {
        float di = dinv[row];
        float f0 = x[row * DFEAT + 2 * col] * di;
        float f1 = x[row * DFEAT + 2 * col + 1] * di;
        unsigned u0 = __float_as_uint(f0); u0 = (u0 + 0x7fffu + ((u0 >> 16) & 1u)) >> 16;
        unsigned u1 = __float_as_uint(f1); u1 = (u1 + 0x7fffu + ((u1 >> 16) & 1u)) >> 16;
        v = (u0 & 0xffffu) | (u1 << 16);
    }
    xs[i] = v;
}

// ---- Persistent fused DUAL-NODE gather -> shared GEMM(+bias) -> expmap0 -> proj ----
// Each wave handles 2 nodes per iteration with interleaved gather loops (2x MLP).
__global__ __launch_bounds__(256) void agg_kernel(const int* __restrict__ begs,
                                                  const int* __restrict__ lens,
                                                  const int* __restrict__ srcs,
                                                  const float* __restrict__ dinv,
                                                  const uint2* __restrict__ xs2,
                                                  const float* __restrict__ W,
                                                  const float* __restrict__ b,
                                                  float* __restrict__ out,
                                                  int n, int noctets) {
    __shared__ float Wl[DFEAT * DFEAT];   // 16 KB
    __shared__ float xl[8][DFEAT];
    int t = threadIdx.x;
    #pragma unroll
    for (int i = 0; i < 16; ++i) Wl[i * 256 + t] = W[i * 256 + t];
    __syncthreads();   // the ONLY barrier

    int r = t >> 6, lane = t & 63;
    int g = lane >> 4;        // edge group (0..3)
    int q = lane & 15;        // uint2 column -> features 4q..4q+3
    float bias = b[lane];

    for (int oct = blockIdx.x; oct < noctets; oct += gridDim.x) {
        int na = oct * 8 + r;
        int nb_ = na + 4;
        bool va = na < n, vb = nb_ < n;
        if (!va) continue;

        int beg0 = begs[na],  end0 = beg0 + lens[na];
        int beg1 = 0, end1 = 0;
        if (vb) { beg1 = begs[nb_]; end1 = beg1 + lens[nb_]; }

        float a0 = 0, a1 = 0, a2 = 0, a3 = 0;
        float b0 = 0, b1 = 0, b2 = 0, b3 = 0;
        int base0 = beg0, base1 = beg1;
        while (base0 < end0 || base1 < end1) {
            int m0 = end0 - base0; m0 = m0 < 0 ? 0 : (m0 > 64 ? 64 : m0);
            int m1 = end1 - base1; m1 = m1 < 0 ? 0 : (m1 > 64 ? 64 : m1);
            int idx0 = 0, idx1 = 0;
            if (lane < m0) idx0 = srcs[base0 + lane];
            if (lane < m1) idx1 = srcs[base1 + lane];
            int q0 = m0 >> 2, q1 = m1 >> 2;
            int qc = q0 < q1 ? q0 : q1;
            for (int j = 0; j < qc; ++j) {
                int sv0 = __shfl(idx0, 4 * j + g, 64);
                int sv1 = __shfl(idx1, 4 * j + g, 64);
                uint2 d0 = xs2[(unsigned)sv0 * 16 + q];
                uint2 d1 = xs2[(unsigned)sv1 * 16 + q];
                a0 += __uint_as_float(d0.x << 16);
                a1 += __uint_as_float(d0.x & 0xffff0000u);
                a2 += __uint_as_float(d0.y << 16);
                a3 += __uint_as_float(d0.y & 0xffff0000u);
                b0 += __uint_as_float(d1.x << 16);
                b1 += __uint_as_float(d1.x & 0xffff0000u);
                b2 += __uint_as_float(d1.y << 16);
                b3 += __uint_as_float(d1.y & 0xffff0000u);
            }
            for (int j = qc; j < q0; ++j) {
                int sv0 = __shfl(idx0, 4 * j + g, 64);
                uint2 d0 = xs2[(unsigned)sv0 * 16 + q];
                a0 += __uint_as_float(d0.x << 16);
                a1 += __uint_as_float(d0.x & 0xffff0000u);
                a2 += __uint_as_float(d0.y << 16);
                a3 += __uint_as_float(d0.y & 0xffff0000u);
            }
            for (int j = qc; j < q1; ++j) {
                int sv1 = __shfl(idx1, 4 * j + g, 64);
                uint2 d1 = xs2[(unsigned)sv1 * 16 + q];
                b0 += __uint_as_float(d1.x << 16);
                b1 += __uint_as_float(d1.x & 0xffff0000u);
                b2 += __uint_as_float(d1.y << 16);
                b3 += __uint_as_float(d1.y & 0xffff0000u);
            }
            base0 += 64; base1 += 64;
        }
        #pragma unroll
        for (int off = 16; off < 64; off <<= 1) {
            a0 += __shfl_xor(a0, off, 64);
            a1 += __shfl_xor(a1, off, 64);
            a2 += __shfl_xor(a2, off, 64);
            a3 += __shfl_xor(a3, off, 64);
            b0 += __shfl_xor(b0, off, 64);
            b1 += __shfl_xor(b1, off, 64);
            b2 += __shfl_xor(b2, off, 64);
            b3 += __shfl_xor(b3, off, 64);
        }
        if (g == 0) {
            float dia = dinv[na];
            xl[r][4 * q + 0] = a0 * dia;
            xl[r][4 * q + 1] = a1 * dia;
            xl[r][4 * q + 2] = a2 * dia;
            xl[r][4 * q + 3] = a3 * dia;
            if (vb) {
                float dib = dinv[nb_];
                xl[r + 4][4 * q + 0] = b0 * dib;
                xl[r + 4][4 * q + 1] = b1 * dib;
                xl[r + 4][4 * q + 2] = b2 * dib;
                xl[r + 4][4 * q + 3] = b3 * dib;
            }
        }
        // wave-synchronous LDS: same wave wrote xl rows r / r+4, same wave reads.

        float oa0 = bias, oa1 = 0.0f, ob0 = bias, ob1 = 0.0f;
        #pragma unroll
        for (int k = 0; k < DFEAT; k += 2) {
            float w0 = Wl[k * DFEAT + lane];
            float w1 = Wl[(k + 1) * DFEAT + lane];
            oa0 = fmaf(xl[r][k],     w0, oa0);
            oa1 = fmaf(xl[r][k + 1], w1, oa1);
            ob0 = fmaf(xl[r + 4][k],     w0, ob0);
            ob1 = fmaf(xl[r + 4][k + 1], w1, ob1);
        }
        float oa = oa0 + oa1;
        float ob = ob0 + ob1;

        float ssa = oa * oa, ssb = ob * ob;
        #pragma unroll
        for (int off = 32; off > 0; off >>= 1) {
            ssa += __shfl_xor(ssa, off, 64);
            ssb += __shfl_xor(ssb, off, 64);
        }
        float norma = fmaxf(sqrtf(ssa), 1e-15f);
        float sca = fminf(tanhf(norma), 1.0f - 4e-3f) / norma;
        out[(long long)na * DFEAT + lane] = oa * sca;
        if (vb) {
            float normb = fmaxf(sqrtf(ssb), 1e-15f);
            float scb = fminf(tanhf(normb), 1.0f - 4e-3f) / normb;
            out[(long long)nb_ * DFEAT + lane] = ob * scb;
        }
    }
}

// ---------------- launch ----------------

extern "C" void kernel_launch(void* const* d_in, const int* in_sizes, int n_in,
                              void* d_out, int out_size, void* d_ws, size_t ws_size,
                              hipStream_t stream) {
    const float* x = (const float*)d_in[0];
    const float* W = (const float*)d_in[1];
    const float* b = (const float*)d_in[2];
    const int* ei  = (const int*)d_in[3];

    int n = in_sizes[0] / DFEAT;           // 100000
    int E = in_sizes[3] / 2;               // 1200000
    int NB = (n + NPB - 1) / NPB;          // 391 buckets
    int nblk = (E + EPB - 1) / EPB;        // 147 partition blocks
    int noctets = (n + 7) / 8;             // 12500

    // workspace layout (ints): ~20.8 MB
    int* blkhistT    = (int*)d_ws;                         // 512*nblk
    int* buckettotal = blkhistT + 512 * nblk;              // 512
    int* bucketbase  = buckettotal + 512;                  // 513 (+pad)
    int* srcs        = bucketbase + 516;                   // E + NB*4*NPB
    int* begs        = srcs + E + NB * 4 * NPB;            // n
    int* lens        = begs + n;                           // n
    float* dinv      = (float*)(lens + n);                 // n
    unsigned* ebuf   = (unsigned*)(dinv + n);              // union: E (ebuf) then (n+1)*32 (xs)
    unsigned* xs     = ebuf;                               // xs overlays ebuf (ebuf dead after csrD)

    float* out = (float*)d_out;

    int aggblocks = 2048;                  // 8 blocks/CU (LDS-limited residency)
    if (aggblocks > noctets) aggblocks = noctets;

    histA_kernel <<<nblk, 256, 0, stream>>>(ei, blkhistT, E, nblk);
    scanB1_kernel<<<512, 256, 0, stream>>>(blkhistT, buckettotal, nblk);
    scanB2_kernel<<<1, 512, 0, stream>>>(buckettotal, bucketbase);
    partC_kernel <<<nblk, 256, 0, stream>>>(ei, blkhistT, bucketbase, ebuf, E, nblk);
    csrD_kernel  <<<NB, 256, 0, stream>>>(ebuf, bucketbase, srcs, begs, lens, dinv, n);
    xsprep_kernel<<<((n + 1) * 32 + 255) / 256, 256, 0, stream>>>(x, dinv, xs, n);
    agg_kernel   <<<aggblocks, 256, 0, stream>>>(begs, lens, srcs, dinv,
                                                 (const uint2*)xs, W, b, out, n, noctets);
}